// Round 7
// baseline (11960.561 us; speedup 1.0000x reference)
//
#include <hip/hip_runtime.h>
#include <math.h>

// Problem constants (match reference file)
#define BATCH 4
#define NPTS 16384
#define M 4096          // centers per cloud = RATIO * NPTS
#define MAX_NB 64
#define R2F 0.0625f     // R*R = 0.25*0.25 (exactly representable)
#define FPS_T 1024      // threads per FPS block
#define PPT 16          // points per thread = NPTS / FPS_T

// Semantics (A): op-by-op rounding for the neighbor phase. Contraction off.
__device__ __forceinline__ float dist2_seq(
    float a0, float a1, float a2, float a3, float a4, float a5,
    float b0, float b1, float b2, float b3, float b4, float b5) {
#pragma clang fp contract(off)
  float d0 = a0 - b0; float s = d0 * d0;
  float d1 = a1 - b1; s = s + d1 * d1;
  float d2 = a2 - b2; s = s + d2 * d2;
  float d3 = a3 - b3; s = s + d3 * d3;
  float d4 = a4 - b4; s = s + d4 * d4;
  float d5 = a5 - b5; s = s + d5 * d5;
  return s;
}

__device__ __forceinline__ float rfl_f(float v) {
  return __int_as_float(__builtin_amdgcn_readfirstlane(__float_as_int(v)));
}

// ---------------------------------------------------------------------------
// R6 post-mortem: local ARRAYS (c0[16]...mind[16]) never became registers —
// SROA runs before unrolling, sees variable indices, lowers them to scratch;
// AMDGPUPromoteAlloca only rescues a small byte budget (VGPR_Count stuck at
// 64 across every geometry/attribute). Timing matched L2-bound scratch
// reloads (~6750 cyc/pick). Fix: NO ARRAYS — 112 macro-generated NAMED
// SCALARS (pure SSA; RA must keep them in VGPRs). Keep the 82944 B LDS
// (1 block/CU -> 4 waves/EU -> 128-VGPR budget) + waves_per_eu(4,4).
// Semantics identical to the verified R6 kernel (absmax 0.0):
// XLA-fused fma-chain distances, fmin, strict-> argmax with first-index
// tie-break, winner publishes its registers to LDS.
// ---------------------------------------------------------------------------
#define DECL_PT(J) float a0_##J, a1_##J, a2_##J, a3_##J, a4_##J, a5_##J, md_##J;
#define LOAD_PT(J)                       \
  {                                      \
    const int p = (J)*FPS_T + t;         \
    a0_##J = xb[3 * p + 0];              \
    a1_##J = xb[3 * p + 1];              \
    a2_##J = xb[3 * p + 2];              \
    a3_##J = pb[3 * p + 0];              \
    a4_##J = pb[3 * p + 1];              \
    a5_##J = pb[3 * p + 2];              \
    md_##J = INFINITY;                   \
  }
// XLA scan-body semantics (B): fma chain, seq order (verified bit-exact).
#define UPD_PT(J)                                   \
  {                                                 \
    float d0 = a0_##J - fx0;                        \
    float s = __builtin_fmaf(d0, d0, 0.0f);         \
    float d1 = a1_##J - fx1;                        \
    s = __builtin_fmaf(d1, d1, s);                  \
    float d2 = a2_##J - fx2;                        \
    s = __builtin_fmaf(d2, d2, s);                  \
    float d3 = a3_##J - fx3;                        \
    s = __builtin_fmaf(d3, d3, s);                  \
    float d4 = a4_##J - fx4;                        \
    s = __builtin_fmaf(d4, d4, s);                  \
    float d5 = a5_##J - fx5;                        \
    s = __builtin_fmaf(d5, d5, s);                  \
    const float nm = fminf(md_##J, s);              \
    md_##J = nm;                                    \
    if (nm > bestv) { /* strict >: earliest J */    \
      bestv = nm;                                   \
      bestj = (J);                                  \
    }                                               \
  }
#define PUB_PT(J)                        \
  if (jj == (J)) {                       \
    sc[0] = a0_##J;                      \
    sc[1] = a1_##J;                      \
    sc[2] = a2_##J;                      \
    sc[3] = a3_##J;                      \
    sc[4] = a4_##J;                      \
    sc[5] = a5_##J;                      \
  }
#define FOR16(F) \
  F(0) F(1) F(2) F(3) F(4) F(5) F(6) F(7) \
  F(8) F(9) F(10) F(11) F(12) F(13) F(14) F(15)

__global__ __launch_bounds__(FPS_T)
__attribute__((amdgpu_waves_per_eu(4, 4)))
void fps_kernel(
    const float* __restrict__ x, const float* __restrict__ pos,
    float* __restrict__ out) {
  // 20736 floats = 82944 B > 81920 B (160 KiB / 2) => exactly 1 block/CU.
  __shared__ float s_big[20736];
  float* sc = s_big;               // [0..5]  current center coords
  float* s_rv = s_big + 8;         // [8..23] per-wave argmax value
  int* s_ri = (int*)(s_big + 24);  // [24..39] per-wave argmax index

  const int b = blockIdx.x;
  const int t = threadIdx.x;
  const int lane = t & 63;
  const float* xb = x + (size_t)b * NPTS * 3;
  const float* pb = pos + (size_t)b * NPTS * 3;

  float* out_pos = out + (size_t)BATCH * M * 3;              // second output
  int* idx_stash = (int*)(out + (size_t)2 * BATCH * M * 3);  // batch region

  // 112 named scalars: 16 points x (6 coords + mind). No allocas.
  FOR16(DECL_PT)
  FOR16(LOAD_PT)

  // Seed: pick 0 is point 0, owned by thread 0 (J=0).
  if (t == 0) {
    sc[0] = a0_0; sc[1] = a1_0; sc[2] = a2_0;
    sc[3] = a3_0; sc[4] = a4_0; sc[5] = a5_0;
  }
  __syncthreads();

  int g = 0;  // current pick (global point index within cloud)
  for (int k = 0; k < M; ++k) {
    // Center coords: LDS broadcast -> SGPRs.
    const float fx0 = rfl_f(sc[0]);
    const float fx1 = rfl_f(sc[1]);
    const float fx2 = rfl_f(sc[2]);
    const float fx3 = rfl_f(sc[3]);
    const float fx4 = rfl_f(sc[4]);
    const float fx5 = rfl_f(sc[5]);

    if (t == 0) {
      idx_stash[b * M + k] = g;                    // for kernel 2
      out_pos[(size_t)(b * M + k) * 3 + 0] = fx3;  // pos[idx_g] (exact copy)
      out_pos[(size_t)(b * M + k) * 3 + 1] = fx4;
      out_pos[(size_t)(b * M + k) * 3 + 2] = fx5;
    }
    if (k == M - 1) break;  // last pick needs no further update/argmax

    float bestv = -1.0f;  // minds are >= 0
    int bestj = 0;
    FOR16(UPD_PT)
    int besti = bestj * FPS_T + t;

    // Wave-level argmax reduce, tie -> smaller index.
#pragma unroll
    for (int off = 32; off > 0; off >>= 1) {
      const float ov = __shfl_xor(bestv, off, 64);
      const int oi = __shfl_xor(besti, off, 64);
      if (ov > bestv || (ov == bestv && oi < besti)) {
        bestv = ov;
        besti = oi;
      }
    }
    const int w = t >> 6;
    if (lane == 0) {
      s_rv[w] = bestv;
      s_ri[w] = besti;
    }
    __syncthreads();  // A: wave results visible; prior sc reads done

    // Every wave redundantly folds the 16 wave-results (uniform result).
    float bv = s_rv[lane & 15];
    int bi = s_ri[lane & 15];
#pragma unroll
    for (int off = 1; off <= 8; off <<= 1) {
      const float ov = __shfl_xor(bv, off, 64);
      const int oi = __shfl_xor(bi, off, 64);
      if (ov > bv || (ov == bv && oi < bi)) {
        bv = ov;
        bi = oi;
      }
    }
    g = bi;  // uniform across the block

    // Winning thread publishes the picked point's coords from registers.
    if (t == (bi & (FPS_T - 1))) {
      const int jj = bi >> 10;  // FPS_T = 1024
      FOR16(PUB_PT)
    }
    __syncthreads();  // B: sc ready for next iteration
  }
}

// ---------------------------------------------------------------------------
// Kernel 2: radius-neighbor capped mean (verified; not the bottleneck).
// ---------------------------------------------------------------------------
#define K2_T 256
__global__ __launch_bounds__(K2_T, 4) void nbr_kernel(
    const float* __restrict__ x, const float* __restrict__ pos,
    float* __restrict__ out) {
  const int lane = threadIdx.x & 63;
  const int w = threadIdx.x >> 6;
  const int cbase = blockIdx.x * 16 + w * 4;  // 4 centers per wave

  const int* idx_stash = (const int*)(out + (size_t)2 * BATCH * M * 3);
  float* out_x = out;
  float* out_batch = out + (size_t)2 * BATCH * M * 3;

  const int b = cbase / M;  // all 16 centers of a block share a cloud
  const float* xb = x + (size_t)b * NPTS * 3;
  const float* pb = pos + (size_t)b * NPTS * 3;

  float cc0[4], cc1[4], cc2[4], cc3[4], cc4[4], cc5[4];
#pragma unroll
  for (int i = 0; i < 4; ++i) {
    const int c = idx_stash[cbase + i];  // local index within cloud
    cc0[i] = xb[3 * c + 0];
    cc1[i] = xb[3 * c + 1];
    cc2[i] = xb[3 * c + 2];
    cc3[i] = pb[3 * c + 0];
    cc4[i] = pb[3 * c + 1];
    cc5[i] = pb[3 * c + 2];
  }

  float s0[4] = {0, 0, 0, 0}, s1[4] = {0, 0, 0, 0}, s2[4] = {0, 0, 0, 0};
  int cnt[4] = {0, 0, 0, 0};

  for (int p = lane; p < NPTS; p += 64) {
    const float x0 = xb[3 * p + 0];
    const float x1 = xb[3 * p + 1];
    const float x2 = xb[3 * p + 2];
    const float q0 = pb[3 * p + 0];
    const float q1 = pb[3 * p + 1];
    const float q2 = pb[3 * p + 2];
#pragma unroll
    for (int i = 0; i < 4; ++i) {
      const float d2 = dist2_seq(cc0[i], cc1[i], cc2[i], cc3[i], cc4[i],
                                 cc5[i], x0, x1, x2, q0, q1, q2);
      if (d2 <= R2F) {
        cnt[i] += 1;
        s0[i] += x0;
        s1[i] += x1;
        s2[i] += x2;
      }
    }
  }

#pragma unroll
  for (int i = 0; i < 4; ++i) {
#pragma unroll
    for (int off = 32; off > 0; off >>= 1) {
      s0[i] += __shfl_xor(s0[i], off, 64);
      s1[i] += __shfl_xor(s1[i], off, 64);
      s2[i] += __shfl_xor(s2[i], off, 64);
      cnt[i] += __shfl_xor(cnt[i], off, 64);
    }
  }

#pragma unroll
  for (int i = 0; i < 4; ++i) {
    const int total = cnt[i];
    float m0, m1, m2;
    if (total <= MAX_NB) {
      const float denom = (float)total;  // >= 1 (self is always in range)
      m0 = s0[i] / denom;
      m1 = s1[i] / denom;
      m2 = s2[i] / denom;
    } else {
      // Exact first-64-by-index fallback (wave-uniform branch, rare).
      const int base = lane * (NPTS / 64);
      int lc = 0;
      for (int p = base; p < base + NPTS / 64; ++p) {
        const float d2 =
            dist2_seq(cc0[i], cc1[i], cc2[i], cc3[i], cc4[i], cc5[i],
                      xb[3 * p + 0], xb[3 * p + 1], xb[3 * p + 2],
                      pb[3 * p + 0], pb[3 * p + 1], pb[3 * p + 2]);
        if (d2 <= R2F) lc += 1;
      }
      int pre = 0;
      for (int l = 0; l < 64; ++l) {
        const int c = __shfl(lc, l, 64);
        if (l < lane) pre += c;
      }
      float t0 = 0, t1 = 0, t2 = 0;
      int r = pre;
      for (int p = base; p < base + NPTS / 64; ++p) {
        const float x0 = xb[3 * p + 0], x1 = xb[3 * p + 1],
                    x2 = xb[3 * p + 2];
        const float d2 =
            dist2_seq(cc0[i], cc1[i], cc2[i], cc3[i], cc4[i], cc5[i], x0, x1,
                      x2, pb[3 * p + 0], pb[3 * p + 1], pb[3 * p + 2]);
        if (d2 <= R2F) {
          if (r < MAX_NB) {
            t0 += x0;
            t1 += x1;
            t2 += x2;
          }
          r += 1;
        }
      }
#pragma unroll
      for (int off = 32; off > 0; off >>= 1) {
        t0 += __shfl_xor(t0, off, 64);
        t1 += __shfl_xor(t1, off, 64);
        t2 += __shfl_xor(t2, off, 64);
      }
      m0 = t0 / 64.0f;
      m1 = t1 / 64.0f;
      m2 = t2 / 64.0f;
    }
    if (lane == i) {
      const int gc = cbase + i;
      out_x[(size_t)gc * 3 + 0] = m0;
      out_x[(size_t)gc * 3 + 1] = m1;
      out_x[(size_t)gc * 3 + 2] = m2;
      out_batch[gc] = (float)b;  // batch ids as float in the float32 buffer
    }
  }
}

extern "C" void kernel_launch(void* const* d_in, const int* in_sizes, int n_in,
                              void* d_out, int out_size, void* d_ws,
                              size_t ws_size, hipStream_t stream) {
  (void)in_sizes;
  (void)n_in;
  (void)out_size;
  (void)d_ws;
  (void)ws_size;
  const float* x = (const float*)d_in[0];
  const float* pos = (const float*)d_in[1];
  // d_in[2] (batch) is implied by the contiguous equal-size layout.
  float* out = (float*)d_out;

  fps_kernel<<<BATCH, FPS_T, 0, stream>>>(x, pos, out);
  nbr_kernel<<<(BATCH * M) / 16, K2_T, 0, stream>>>(x, pos, out);
}

// Round 8
// 11036.293 us; speedup vs baseline: 1.0837x; 1.0837x over previous
//
#include <hip/hip_runtime.h>
#include <math.h>

// Problem constants (match reference file)
#define BATCH 4
#define NPTS 16384
#define M 4096          // centers per cloud = RATIO * NPTS
#define MAX_NB 64
#define R2F 0.0625f     // R*R = 0.25*0.25 (exactly representable)
#define W 4             // workgroups per cloud
#define FPS_T 1024      // threads per FPS workgroup
#define PPT 4           // points per thread = NPTS / (W * FPS_T)
#define SEG (NPTS / W)  // 4096 points owned per workgroup

// Semantics (A): op-by-op rounding for the neighbor phase. Contraction off.
__device__ __forceinline__ float dist2_seq(
    float a0, float a1, float a2, float a3, float a4, float a5,
    float b0, float b1, float b2, float b3, float b4, float b5) {
#pragma clang fp contract(off)
  float d0 = a0 - b0; float s = d0 * d0;
  float d1 = a1 - b1; s = s + d1 * d1;
  float d2 = a2 - b2; s = s + d2 * d2;
  float d3 = a3 - b3; s = s + d3 * d3;
  float d4 = a4 - b4; s = s + d4 * d4;
  float d5 = a5 - b5; s = s + d5 * d5;
  return s;
}

// ---------------------------------------------------------------------------
// R7 post-mortem: VGPR_Count pinned at 64 across every register-side lever;
// one cloud's state (16384 x 7 f32 = 458 KB) ~= a whole CU register file, so
// the backend shuffles it through AGPR/scratch at ~2.3x the ideal inst count
// (11.75 ms plateau, R5-R7). Fix the STRUCTURE: split each cloud's FPS
// across W=4 workgroups -> 28 floats/thread of state (spill-proof), and
// synchronize picks via self-validating tagged 64-bit slots in d_ws using
// relaxed device-scope atomics (payload inside the word -> no fences).
//   slot = [f32 bestv (bit63=0) | 12-bit pick tag | 20-bit global index]
// Re-poison safety: 0xAAAAAAAA... poison has tag field 0xAAA=2730, never
// equal to the expected tag at first use (k=1,2). Parity-2 slot reuse is
// race-free: WG A overwrites its k-slot only when publishing k+2, which
// requires A passed poll(k+1), which requires every WG published k+1,
// which requires (via their update-k barrier) they fully consumed k-slots.
// Math/tie-breaks identical to the verified R3-R7 kernels (absmax 0.0):
// XLA-fused fma-chain d2, fminf, strict-> argmax, smallest-global-index tie.
// ---------------------------------------------------------------------------
#define DECL_PT(J) float a0_##J, a1_##J, a2_##J, a3_##J, a4_##J, a5_##J, md_##J;
#define LOAD_PT(J)                         \
  {                                        \
    const int p = pbase + (J)*FPS_T + t;   \
    a0_##J = xb[3 * p + 0];                \
    a1_##J = xb[3 * p + 1];                \
    a2_##J = xb[3 * p + 2];                \
    a3_##J = pb[3 * p + 0];                \
    a4_##J = pb[3 * p + 1];                \
    a5_##J = pb[3 * p + 2];                \
    md_##J = INFINITY;                     \
  }
#define UPD_PT(J)                                   \
  {                                                 \
    float d0 = a0_##J - fx0;                        \
    float s = __builtin_fmaf(d0, d0, 0.0f);         \
    float d1 = a1_##J - fx1;                        \
    s = __builtin_fmaf(d1, d1, s);                  \
    float d2 = a2_##J - fx2;                        \
    s = __builtin_fmaf(d2, d2, s);                  \
    float d3 = a3_##J - fx3;                        \
    s = __builtin_fmaf(d3, d3, s);                  \
    float d4 = a4_##J - fx4;                        \
    s = __builtin_fmaf(d4, d4, s);                  \
    float d5 = a5_##J - fx5;                        \
    s = __builtin_fmaf(d5, d5, s);                  \
    const float nm = fminf(md_##J, s);              \
    md_##J = nm;                                    \
    if (nm > bestv) { /* strict >: earliest J */    \
      bestv = nm;                                   \
      bestj = (J);                                  \
    }                                               \
  }
#define FOR4(F) F(0) F(1) F(2) F(3)

__global__ __launch_bounds__(FPS_T) void fps_kernel(
    const float* __restrict__ x, const float* __restrict__ pos,
    float* __restrict__ out, unsigned long long* __restrict__ slots) {
  __shared__ float s_rv[2][16];
  __shared__ int s_ri[2][16];

  const int blk = blockIdx.x;
  const int b = blk >> 2;  // cloud
  const int w = blk & 3;   // workgroup within cloud
  const int t = threadIdx.x;
  const int lane = t & 63;
  const int wv = t >> 6;          // wave 0..15
  const int pbase = w * SEG;      // first global point this WG owns

  const float* xb = x + (size_t)b * NPTS * 3;
  const float* pb = pos + (size_t)b * NPTS * 3;

  float* out_pos = out + (size_t)BATCH * M * 3;              // second output
  int* idx_stash = (int*)(out + (size_t)2 * BATCH * M * 3);  // batch region

  // 28 named scalars of state: 4 points x (6 coords + mind).
  FOR4(DECL_PT)
  FOR4(LOAD_PT)

  int g = 0;  // pick 0 is global point 0 (known to every WG; no poll)
  for (int k = 0; k < M; ++k) {
    if (k > 0) {
      // Poll the W=4 tagged slots for pick k; every lane owns slot lane&3,
      // so a 2-level xor-fold leaves the global winner in EVERY lane.
      const unsigned long long* sp =
          slots + ((size_t)(k & 1) * BATCH + b) * W;
      unsigned long long v;
      bool ok;
      do {
        v = __hip_atomic_load(&sp[lane & 3], __ATOMIC_RELAXED,
                              __HIP_MEMORY_SCOPE_AGENT);
        ok = (((unsigned)v >> 20) & 0xFFFu) == (unsigned)(k & 0xFFF);
      } while (!__all(ok));
      float bv = __uint_as_float((unsigned)(v >> 32));
      int bp = (int)((unsigned)v & 0xFFFFFu);
#pragma unroll
      for (int off = 1; off <= 2; off <<= 1) {
        const float ov = __shfl_xor(bv, off, 64);
        const int op = __shfl_xor(bp, off, 64);
        if (ov > bv || (ov == bv && op < bp)) {
          bv = ov;
          bp = op;
        }
      }
      g = bp;  // uniform
    }
    const int gs = __builtin_amdgcn_readfirstlane(g);

    // Center coords from the (L2-hot) inputs; uniform address.
    const float fx0 = xb[3 * gs + 0];
    const float fx1 = xb[3 * gs + 1];
    const float fx2 = xb[3 * gs + 2];
    const float fx3 = pb[3 * gs + 0];
    const float fx4 = pb[3 * gs + 1];
    const float fx5 = pb[3 * gs + 2];

    if (w == 0 && t == 0) {
      idx_stash[b * M + k] = gs;                   // for kernel 2
      out_pos[(size_t)(b * M + k) * 3 + 0] = fx3;  // pos[idx_g] (exact copy)
      out_pos[(size_t)(b * M + k) * 3 + 1] = fx4;
      out_pos[(size_t)(b * M + k) * 3 + 2] = fx5;
    }
    if (k == M - 1) break;  // last pick: no update/publish needed

    // Update my 4 points; track (max, first-J).
    float bestv = -1.0f;
    int bestj = 0;
    FOR4(UPD_PT)
    int besti = pbase + bestj * FPS_T + t;  // global index (blocked layout)

    // Wave argmax (tie -> smaller global index).
#pragma unroll
    for (int off = 32; off > 0; off >>= 1) {
      const float ov = __shfl_xor(bestv, off, 64);
      const int oi = __shfl_xor(besti, off, 64);
      if (ov > bestv || (ov == bestv && oi < besti)) {
        bestv = ov;
        besti = oi;
      }
    }
    const int par = (k + 1) & 1;
    if (lane == 0) {
      s_rv[par][wv] = bestv;
      s_ri[par][wv] = besti;
    }
    __syncthreads();  // the only barrier per pick

    // Wave 0 folds the 16 wave-results and publishes this WG's candidate.
    if (wv == 0) {
      float bv = s_rv[par][lane & 15];
      int bi = s_ri[par][lane & 15];
#pragma unroll
      for (int off = 1; off <= 8; off <<= 1) {
        const float ov = __shfl_xor(bv, off, 64);
        const int oi = __shfl_xor(bi, off, 64);
        if (ov > bv || (ov == bv && oi < bi)) {
          bv = ov;
          bi = oi;
        }
      }
      if (lane == 0) {
        const unsigned long long pk =
            ((unsigned long long)__float_as_uint(bv) << 32) |
            ((unsigned long long)((unsigned)((k + 1) & 0xFFF)) << 20) |
            (unsigned long long)(unsigned)bi;
        __hip_atomic_store(&slots[((size_t)par * BATCH + b) * W + w], pk,
                           __ATOMIC_RELAXED, __HIP_MEMORY_SCOPE_AGENT);
      }
    }
  }
}

// ---------------------------------------------------------------------------
// Kernel 2: radius-neighbor capped mean (verified; not the bottleneck).
// ---------------------------------------------------------------------------
#define K2_T 256
__global__ __launch_bounds__(K2_T, 4) void nbr_kernel(
    const float* __restrict__ x, const float* __restrict__ pos,
    float* __restrict__ out) {
  const int lane = threadIdx.x & 63;
  const int w = threadIdx.x >> 6;
  const int cbase = blockIdx.x * 16 + w * 4;  // 4 centers per wave

  const int* idx_stash = (const int*)(out + (size_t)2 * BATCH * M * 3);
  float* out_x = out;
  float* out_batch = out + (size_t)2 * BATCH * M * 3;

  const int b = cbase / M;  // all 16 centers of a block share a cloud
  const float* xb = x + (size_t)b * NPTS * 3;
  const float* pb = pos + (size_t)b * NPTS * 3;

  float cc0[4], cc1[4], cc2[4], cc3[4], cc4[4], cc5[4];
#pragma unroll
  for (int i = 0; i < 4; ++i) {
    const int c = idx_stash[cbase + i];  // local index within cloud
    cc0[i] = xb[3 * c + 0];
    cc1[i] = xb[3 * c + 1];
    cc2[i] = xb[3 * c + 2];
    cc3[i] = pb[3 * c + 0];
    cc4[i] = pb[3 * c + 1];
    cc5[i] = pb[3 * c + 2];
  }

  float s0[4] = {0, 0, 0, 0}, s1[4] = {0, 0, 0, 0}, s2[4] = {0, 0, 0, 0};
  int cnt[4] = {0, 0, 0, 0};

  for (int p = lane; p < NPTS; p += 64) {
    const float x0 = xb[3 * p + 0];
    const float x1 = xb[3 * p + 1];
    const float x2 = xb[3 * p + 2];
    const float q0 = pb[3 * p + 0];
    const float q1 = pb[3 * p + 1];
    const float q2 = pb[3 * p + 2];
#pragma unroll
    for (int i = 0; i < 4; ++i) {
      const float d2 = dist2_seq(cc0[i], cc1[i], cc2[i], cc3[i], cc4[i],
                                 cc5[i], x0, x1, x2, q0, q1, q2);
      if (d2 <= R2F) {
        cnt[i] += 1;
        s0[i] += x0;
        s1[i] += x1;
        s2[i] += x2;
      }
    }
  }

#pragma unroll
  for (int i = 0; i < 4; ++i) {
#pragma unroll
    for (int off = 32; off > 0; off >>= 1) {
      s0[i] += __shfl_xor(s0[i], off, 64);
      s1[i] += __shfl_xor(s1[i], off, 64);
      s2[i] += __shfl_xor(s2[i], off, 64);
      cnt[i] += __shfl_xor(cnt[i], off, 64);
    }
  }

#pragma unroll
  for (int i = 0; i < 4; ++i) {
    const int total = cnt[i];
    float m0, m1, m2;
    if (total <= MAX_NB) {
      const float denom = (float)total;  // >= 1 (self is always in range)
      m0 = s0[i] / denom;
      m1 = s1[i] / denom;
      m2 = s2[i] / denom;
    } else {
      // Exact first-64-by-index fallback (wave-uniform branch, rare).
      const int base = lane * (NPTS / 64);
      int lc = 0;
      for (int p = base; p < base + NPTS / 64; ++p) {
        const float d2 =
            dist2_seq(cc0[i], cc1[i], cc2[i], cc3[i], cc4[i], cc5[i],
                      xb[3 * p + 0], xb[3 * p + 1], xb[3 * p + 2],
                      pb[3 * p + 0], pb[3 * p + 1], pb[3 * p + 2]);
        if (d2 <= R2F) lc += 1;
      }
      int pre = 0;
      for (int l = 0; l < 64; ++l) {
        const int c = __shfl(lc, l, 64);
        if (l < lane) pre += c;
      }
      float t0 = 0, t1 = 0, t2 = 0;
      int r = pre;
      for (int p = base; p < base + NPTS / 64; ++p) {
        const float x0 = xb[3 * p + 0], x1 = xb[3 * p + 1],
                    x2 = xb[3 * p + 2];
        const float d2 =
            dist2_seq(cc0[i], cc1[i], cc2[i], cc3[i], cc4[i], cc5[i], x0, x1,
                      x2, pb[3 * p + 0], pb[3 * p + 1], pb[3 * p + 2]);
        if (d2 <= R2F) {
          if (r < MAX_NB) {
            t0 += x0;
            t1 += x1;
            t2 += x2;
          }
          r += 1;
        }
      }
#pragma unroll
      for (int off = 32; off > 0; off >>= 1) {
        t0 += __shfl_xor(t0, off, 64);
        t1 += __shfl_xor(t1, off, 64);
        t2 += __shfl_xor(t2, off, 64);
      }
      m0 = t0 / 64.0f;
      m1 = t1 / 64.0f;
      m2 = t2 / 64.0f;
    }
    if (lane == i) {
      const int gc = cbase + i;
      out_x[(size_t)gc * 3 + 0] = m0;
      out_x[(size_t)gc * 3 + 1] = m1;
      out_x[(size_t)gc * 3 + 2] = m2;
      out_batch[gc] = (float)b;  // batch ids as float in the float32 buffer
    }
  }
}

extern "C" void kernel_launch(void* const* d_in, const int* in_sizes, int n_in,
                              void* d_out, int out_size, void* d_ws,
                              size_t ws_size, hipStream_t stream) {
  (void)in_sizes;
  (void)n_in;
  (void)out_size;
  (void)ws_size;
  const float* x = (const float*)d_in[0];
  const float* pos = (const float*)d_in[1];
  // d_in[2] (batch) is implied by the contiguous equal-size layout.
  float* out = (float*)d_out;
  unsigned long long* slots = (unsigned long long*)d_ws;  // 2*B*W u64 = 256 B

  fps_kernel<<<BATCH * W, FPS_T, 0, stream>>>(x, pos, out, slots);
  nbr_kernel<<<(BATCH * M) / 16, K2_T, 0, stream>>>(x, pos, out);
}

// Round 9
// 10149.677 us; speedup vs baseline: 1.1784x; 1.0874x over previous
//
#include <hip/hip_runtime.h>
#include <math.h>

// Problem constants (match reference file)
#define BATCH 4
#define NPTS 16384
#define M 4096          // centers per cloud = RATIO * NPTS
#define MAX_NB 64
#define R2F 0.0625f     // R*R = 0.25*0.25 (exactly representable)
#define W 4             // workgroups per cloud
#define FPS_T 1024      // threads per FPS workgroup
#define SEG (NPTS / W)  // 4096 points owned per workgroup

// Semantics (A): op-by-op rounding for the neighbor phase. Contraction off.
__device__ __forceinline__ float dist2_seq(
    float a0, float a1, float a2, float a3, float a4, float a5,
    float b0, float b1, float b2, float b3, float b4, float b5) {
#pragma clang fp contract(off)
  float d0 = a0 - b0; float s = d0 * d0;
  float d1 = a1 - b1; s = s + d1 * d1;
  float d2 = a2 - b2; s = s + d2 * d2;
  float d3 = a3 - b3; s = s + d3 * d3;
  float d4 = a4 - b4; s = s + d4 * d4;
  float d5 = a5 - b5; s = s + d5 * d5;
  return s;
}

// ---------------------------------------------------------------------------
// R8 post-mortem: split-across-4-WGs fixed the register problem
// (VGPR_Count=28, state in regs) but sync cost ~2.4 us/pick because (1) all
// 16384 threads polled the slots and (2) all 4 clouds' slots shared one
// 128-B line. R9 fixes the sync fabric behavior, protocol unchanged:
//   - slot(b,par,w) = d_ws u64[b*32 + par*16 + w]: one 128-B sector per
//     (cloud,parity) quad, 256 B per cloud -> no false sharing.
//   - only wave 0 lanes 0-3 poll (64 polling lanes chip-wide); winner is
//     broadcast through LDS s_g behind a barrier; waiting waves issue no
//     memory traffic.
//   slot = [f32 bestv | 12-bit pick tag | 20-bit global index]  (tag!=0xAAA
//   poison; parity-2 reuse race-free as proven in R8 header).
// Math/tie-breaks bit-identical to R3-R8 (absmax 0.0).
// ---------------------------------------------------------------------------
#define DECL_PT(J) float a0_##J, a1_##J, a2_##J, a3_##J, a4_##J, a5_##J, md_##J;
#define LOAD_PT(J)                         \
  {                                        \
    const int p = pbase + (J)*FPS_T + t;   \
    a0_##J = xb[3 * p + 0];                \
    a1_##J = xb[3 * p + 1];                \
    a2_##J = xb[3 * p + 2];                \
    a3_##J = pb[3 * p + 0];                \
    a4_##J = pb[3 * p + 1];                \
    a5_##J = pb[3 * p + 2];                \
    md_##J = INFINITY;                     \
  }
#define UPD_PT(J)                                   \
  {                                                 \
    float d0 = a0_##J - fx0;                        \
    float s = __builtin_fmaf(d0, d0, 0.0f);         \
    float d1 = a1_##J - fx1;                        \
    s = __builtin_fmaf(d1, d1, s);                  \
    float d2 = a2_##J - fx2;                        \
    s = __builtin_fmaf(d2, d2, s);                  \
    float d3 = a3_##J - fx3;                        \
    s = __builtin_fmaf(d3, d3, s);                  \
    float d4 = a4_##J - fx4;                        \
    s = __builtin_fmaf(d4, d4, s);                  \
    float d5 = a5_##J - fx5;                        \
    s = __builtin_fmaf(d5, d5, s);                  \
    const float nm = fminf(md_##J, s);              \
    md_##J = nm;                                    \
    if (nm > bestv) { /* strict >: earliest J */    \
      bestv = nm;                                   \
      bestj = (J);                                  \
    }                                               \
  }
#define FOR4(F) F(0) F(1) F(2) F(3)

__global__ __launch_bounds__(FPS_T) void fps_kernel(
    const float* __restrict__ x, const float* __restrict__ pos,
    float* __restrict__ out, unsigned long long* __restrict__ slots) {
  __shared__ float s_rv[16];
  __shared__ int s_ri[16];
  __shared__ int s_g;

  const int blk = blockIdx.x;
  const int b = blk >> 2;  // cloud
  const int w = blk & 3;   // workgroup within cloud
  const int t = threadIdx.x;
  const int lane = t & 63;
  const int wv = t >> 6;       // wave 0..15
  const int pbase = w * SEG;   // first global point this WG owns

  const float* xb = x + (size_t)b * NPTS * 3;
  const float* pb = pos + (size_t)b * NPTS * 3;

  float* out_pos = out + (size_t)BATCH * M * 3;              // second output
  int* idx_stash = (int*)(out + (size_t)2 * BATCH * M * 3);  // batch region

  // 28 named scalars of state: 4 points x (6 coords + mind).
  FOR4(DECL_PT)
  FOR4(LOAD_PT)

  int g = 0;  // pick 0 is global point 0 (known to every WG; no poll)
  for (int k = 0; k < M; ++k) {
    if (k > 0) {
      if (wv == 0) {
        // Lanes 0-3 poll this cloud's 4 tagged slots for pick k.
        unsigned long long* sp = slots + (size_t)b * 32 + (size_t)(k & 1) * 16;
        unsigned long long v = 0;
        bool ok;
        do {
          if (lane < W) {
            v = __hip_atomic_load(&sp[lane], __ATOMIC_RELAXED,
                                  __HIP_MEMORY_SCOPE_AGENT);
            ok = (((unsigned)v >> 20) & 0xFFFu) == (unsigned)(k & 0xFFF);
          } else {
            ok = true;
          }
        } while (!__all(ok));
        float bv = (lane < W) ? __uint_as_float((unsigned)(v >> 32)) : -1.0f;
        int bp = (int)((unsigned)v & 0xFFFFFu);
#pragma unroll
        for (int off = 1; off <= 2; off <<= 1) {
          const float ov = __shfl_xor(bv, off, 64);
          const int op = __shfl_xor(bp, off, 64);
          if (ov > bv || (ov == bv && op < bp)) {
            bv = ov;
            bp = op;
          }
        }
        if (lane == 0) s_g = bp;  // lanes 0-3 agree; lane 0 publishes
      }
      __syncthreads();  // B1: s_g ready
      g = s_g;
    }
    const int gs = __builtin_amdgcn_readfirstlane(g);

    // Center coords from the (L1/L2-hot) inputs; uniform address.
    const float fx0 = xb[3 * gs + 0];
    const float fx1 = xb[3 * gs + 1];
    const float fx2 = xb[3 * gs + 2];
    const float fx3 = pb[3 * gs + 0];
    const float fx4 = pb[3 * gs + 1];
    const float fx5 = pb[3 * gs + 2];

    if (w == 0 && t == 0) {
      idx_stash[b * M + k] = gs;                   // for kernel 2
      out_pos[(size_t)(b * M + k) * 3 + 0] = fx3;  // pos[idx_g] (exact copy)
      out_pos[(size_t)(b * M + k) * 3 + 1] = fx4;
      out_pos[(size_t)(b * M + k) * 3 + 2] = fx5;
    }
    if (k == M - 1) break;  // last pick: no update/publish needed

    // Update my 4 points; track (max, first-J).
    float bestv = -1.0f;
    int bestj = 0;
    FOR4(UPD_PT)
    int besti = pbase + bestj * FPS_T + t;  // global index (blocked layout)

    // Wave argmax (tie -> smaller global index).
#pragma unroll
    for (int off = 32; off > 0; off >>= 1) {
      const float ov = __shfl_xor(bestv, off, 64);
      const int oi = __shfl_xor(besti, off, 64);
      if (ov > bestv || (ov == bestv && oi < besti)) {
        bestv = ov;
        besti = oi;
      }
    }
    if (lane == 0) {
      s_rv[wv] = bestv;
      s_ri[wv] = besti;
    }
    __syncthreads();  // B2: wave results ready (also isolates s_g WAR)

    // Wave 0 folds the 16 wave-results and publishes this WG's candidate.
    if (wv == 0) {
      float bv = s_rv[lane & 15];
      int bi = s_ri[lane & 15];
#pragma unroll
      for (int off = 1; off <= 8; off <<= 1) {
        const float ov = __shfl_xor(bv, off, 64);
        const int oi = __shfl_xor(bi, off, 64);
        if (ov > bv || (ov == bv && oi < bi)) {
          bv = ov;
          bi = oi;
        }
      }
      if (lane == 0) {
        const unsigned long long pk =
            ((unsigned long long)__float_as_uint(bv) << 32) |
            ((unsigned long long)((unsigned)((k + 1) & 0xFFF)) << 20) |
            (unsigned long long)(unsigned)bi;
        __hip_atomic_store(
            &slots[(size_t)b * 32 + (size_t)((k + 1) & 1) * 16 + w], pk,
            __ATOMIC_RELAXED, __HIP_MEMORY_SCOPE_AGENT);
      }
    }
  }
}

// ---------------------------------------------------------------------------
// Kernel 2: radius-neighbor capped mean (verified; not the bottleneck).
// ---------------------------------------------------------------------------
#define K2_T 256
__global__ __launch_bounds__(K2_T, 4) void nbr_kernel(
    const float* __restrict__ x, const float* __restrict__ pos,
    float* __restrict__ out) {
  const int lane = threadIdx.x & 63;
  const int w = threadIdx.x >> 6;
  const int cbase = blockIdx.x * 16 + w * 4;  // 4 centers per wave

  const int* idx_stash = (const int*)(out + (size_t)2 * BATCH * M * 3);
  float* out_x = out;
  float* out_batch = out + (size_t)2 * BATCH * M * 3;

  const int b = cbase / M;  // all 16 centers of a block share a cloud
  const float* xb = x + (size_t)b * NPTS * 3;
  const float* pb = pos + (size_t)b * NPTS * 3;

  float cc0[4], cc1[4], cc2[4], cc3[4], cc4[4], cc5[4];
#pragma unroll
  for (int i = 0; i < 4; ++i) {
    const int c = idx_stash[cbase + i];  // local index within cloud
    cc0[i] = xb[3 * c + 0];
    cc1[i] = xb[3 * c + 1];
    cc2[i] = xb[3 * c + 2];
    cc3[i] = pb[3 * c + 0];
    cc4[i] = pb[3 * c + 1];
    cc5[i] = pb[3 * c + 2];
  }

  float s0[4] = {0, 0, 0, 0}, s1[4] = {0, 0, 0, 0}, s2[4] = {0, 0, 0, 0};
  int cnt[4] = {0, 0, 0, 0};

  for (int p = lane; p < NPTS; p += 64) {
    const float x0 = xb[3 * p + 0];
    const float x1 = xb[3 * p + 1];
    const float x2 = xb[3 * p + 2];
    const float q0 = pb[3 * p + 0];
    const float q1 = pb[3 * p + 1];
    const float q2 = pb[3 * p + 2];
#pragma unroll
    for (int i = 0; i < 4; ++i) {
      const float d2 = dist2_seq(cc0[i], cc1[i], cc2[i], cc3[i], cc4[i],
                                 cc5[i], x0, x1, x2, q0, q1, q2);
      if (d2 <= R2F) {
        cnt[i] += 1;
        s0[i] += x0;
        s1[i] += x1;
        s2[i] += x2;
      }
    }
  }

#pragma unroll
  for (int i = 0; i < 4; ++i) {
#pragma unroll
    for (int off = 32; off > 0; off >>= 1) {
      s0[i] += __shfl_xor(s0[i], off, 64);
      s1[i] += __shfl_xor(s1[i], off, 64);
      s2[i] += __shfl_xor(s2[i], off, 64);
      cnt[i] += __shfl_xor(cnt[i], off, 64);
    }
  }

#pragma unroll
  for (int i = 0; i < 4; ++i) {
    const int total = cnt[i];
    float m0, m1, m2;
    if (total <= MAX_NB) {
      const float denom = (float)total;  // >= 1 (self is always in range)
      m0 = s0[i] / denom;
      m1 = s1[i] / denom;
      m2 = s2[i] / denom;
    } else {
      // Exact first-64-by-index fallback (wave-uniform branch, rare).
      const int base = lane * (NPTS / 64);
      int lc = 0;
      for (int p = base; p < base + NPTS / 64; ++p) {
        const float d2 =
            dist2_seq(cc0[i], cc1[i], cc2[i], cc3[i], cc4[i], cc5[i],
                      xb[3 * p + 0], xb[3 * p + 1], xb[3 * p + 2],
                      pb[3 * p + 0], pb[3 * p + 1], pb[3 * p + 2]);
        if (d2 <= R2F) lc += 1;
      }
      int pre = 0;
      for (int l = 0; l < 64; ++l) {
        const int c = __shfl(lc, l, 64);
        if (l < lane) pre += c;
      }
      float t0 = 0, t1 = 0, t2 = 0;
      int r = pre;
      for (int p = base; p < base + NPTS / 64; ++p) {
        const float x0 = xb[3 * p + 0], x1 = xb[3 * p + 1],
                    x2 = xb[3 * p + 2];
        const float d2 =
            dist2_seq(cc0[i], cc1[i], cc2[i], cc3[i], cc4[i], cc5[i], x0, x1,
                      x2, pb[3 * p + 0], pb[3 * p + 1], pb[3 * p + 2]);
        if (d2 <= R2F) {
          if (r < MAX_NB) {
            t0 += x0;
            t1 += x1;
            t2 += x2;
          }
          r += 1;
        }
      }
#pragma unroll
      for (int off = 32; off > 0; off >>= 1) {
        t0 += __shfl_xor(t0, off, 64);
        t1 += __shfl_xor(t1, off, 64);
        t2 += __shfl_xor(t2, off, 64);
      }
      m0 = t0 / 64.0f;
      m1 = t1 / 64.0f;
      m2 = t2 / 64.0f;
    }
    if (lane == i) {
      const int gc = cbase + i;
      out_x[(size_t)gc * 3 + 0] = m0;
      out_x[(size_t)gc * 3 + 1] = m1;
      out_x[(size_t)gc * 3 + 2] = m2;
      out_batch[gc] = (float)b;  // batch ids as float in the float32 buffer
    }
  }
}

extern "C" void kernel_launch(void* const* d_in, const int* in_sizes, int n_in,
                              void* d_out, int out_size, void* d_ws,
                              size_t ws_size, hipStream_t stream) {
  (void)in_sizes;
  (void)n_in;
  (void)out_size;
  (void)ws_size;
  const float* x = (const float*)d_in[0];
  const float* pos = (const float*)d_in[1];
  // d_in[2] (batch) is implied by the contiguous equal-size layout.
  float* out = (float*)d_out;
  unsigned long long* slots = (unsigned long long*)d_ws;  // 4*32 u64 = 1 KiB

  fps_kernel<<<BATCH * W, FPS_T, 0, stream>>>(x, pos, out, slots);
  nbr_kernel<<<(BATCH * M) / 16, K2_T, 0, stream>>>(x, pos, out);
}